// Round 4
// baseline (501.499 us; speedup 1.0000x reference)
//
#include <hip/hip_runtime.h>
#include <hip/hip_bf16.h>

#define B_ 4
#define N_ 1024
#define NB_ 32
#define C_ 384
#define CZ_ 128
#define NSITES (B_ * N_)   // 4096
#define EPSV 1e-6f
#define PAD 40             // u16 per LDS row: 32 data + 8 pad (2-way-only bank aliasing = free)
#define SPB 2              // sites per block
#define MR 64              // neighbor rows per block
#define THREADS 512

typedef unsigned short u16;
typedef unsigned int u32;
typedef __bf16 bf16x8 __attribute__((ext_vector_type(8)));
typedef float f32x4 __attribute__((ext_vector_type(4)));

__device__ __forceinline__ u16 f2bf(float f) {
    return __builtin_bit_cast(u16, __float2bfloat16(f));
}
__device__ __forceinline__ u32 pk2(float lo, float hi) {
    return ((u32)f2bf(hi) << 16) | f2bf(lo);
}
__device__ __forceinline__ float bfbits2f(u16 u) {
    union { float f; u32 i; } x;
    x.i = ((u32)u) << 16;
    return x.f;
}

// Wts[d][c] = bf16(W_s[c][d]) (384x384), Wtz[d][z] = bf16(W_z[z][d]) (384x128)
// i.e. ws holds W^T with K contiguous per output-column — exactly the MFMA B-operand order.
__global__ void prep_weights(const float* __restrict__ Ws, const float* __restrict__ Wz,
                             u16* __restrict__ Wts, u16* __restrict__ Wtz) {
    int idx = blockIdx.x * 256 + threadIdx.x;
    if (idx < C_ * C_) {
        int d = idx / C_, c = idx % C_;
        Wts[idx] = f2bf(Ws[c * C_ + d]);
    } else {
        int j = idx - C_ * C_;
        if (j < C_ * CZ_) {
            int d = j / CZ_, z = j % CZ_;
            Wtz[j] = f2bf(Wz[z * C_ + d]);
        }
    }
}

// Block = 512 thr (8 waves), 2 sites (M=64 rows), N=384.
// Wave (mg, ns): mg = site (32 rows), ns = 96-col strip.
// W (B-operand) is read DIRECTLY from global/L2 per fragment — no LDS staging, no W barrier.
// Only A (fp32 HBM stream) goes through LDS (cvt to bf16), double-buffered, 1 barrier/chunk.
__global__ __launch_bounds__(THREADS, 4)
void fused_msg_kernel(const float* __restrict__ s_i,
                      const float* __restrict__ s_ij,
                      const float* __restrict__ m_ij,
                      const float* __restrict__ z_ij,
                      const u16* __restrict__ Wts,
                      const u16* __restrict__ Wtz,
                      const float* __restrict__ gamma,
                      const float* __restrict__ beta,
                      float* __restrict__ out) {
    __shared__ u16 ldsA[2][MR * PAD];    // 2 x 5120 B
    __shared__ float lds_snew[SPB * C_]; //     3072 B   total 13312 B

    const int tid = threadIdx.x;
    const int wave = tid >> 6;
    const int lane = tid & 63;
    const int q = lane >> 4;
    const int ln = lane & 15;
    const int mg = wave >> 2;            // site within the pair
    const int cb = (wave & 3) * 96;      // column strip base

    const int site0 = blockIdx.x * SPB;
    const long rowbase = (long)site0 * NB_;

    // A staging map: thread -> (row 0..63, 4 floats at k=aseg*4)
    const int arow = tid >> 3, aseg = tid & 7;
    const int la_w = arow * PAD + aseg * 4;

    const float mv = m_ij[rowbase + lane];   // per-lane neighbor mask

    const f32x4 ZERO = {0.f, 0.f, 0.f, 0.f};
    f32x4 acc[2][6];
    #pragma unroll
    for (int mt = 0; mt < 2; ++mt)
        #pragma unroll
        for (int nt = 0; nt < 6; ++nt)
            acc[mt][nt] = ZERO;

    float4 ra;

    // -------- Phase 1: gate = z @ Wz (kd=128, NK=4) --------
    {
        const int kd = CZ_;
        const float* ap = z_ij + (rowbase + arow) * kd + aseg * 4;
        const u16* wb = Wtz + (cb + ln) * kd + q * 8;   // per-lane B base, advances by 32 k/chunk

        ra = *reinterpret_cast<const float4*>(ap);
        ap += 32;
        *reinterpret_cast<uint2*>(&ldsA[0][la_w]) = uint2{pk2(ra.x, ra.y), pk2(ra.z, ra.w)};
        __syncthreads();

        #pragma unroll 1
        for (int c = 0; c < 4; ++c) {
            if (c + 1 < 4) { ra = *reinterpret_cast<const float4*>(ap); ap += 32; }
            const u16* lA = ldsA[c & 1];
            bf16x8 a0 = *reinterpret_cast<const bf16x8*>(&lA[(mg * 32 + ln) * PAD + q * 8]);
            bf16x8 a1 = *reinterpret_cast<const bf16x8*>(&lA[(mg * 32 + 16 + ln) * PAD + q * 8]);
            bf16x8 b[6];
            #pragma unroll
            for (int nt = 0; nt < 6; ++nt)
                b[nt] = *reinterpret_cast<const bf16x8*>(wb + nt * 16 * kd);
            wb += 32;
            #pragma unroll
            for (int nt = 0; nt < 6; ++nt) {
                acc[0][nt] = __builtin_amdgcn_mfma_f32_16x16x32_bf16(a0, b[nt], acc[0][nt], 0, 0, 0);
                acc[1][nt] = __builtin_amdgcn_mfma_f32_16x16x32_bf16(a1, b[nt], acc[1][nt], 0, 0, 0);
            }
            if (c + 1 < 4)
                *reinterpret_cast<uint2*>(&ldsA[(c + 1) & 1][la_w]) =
                    uint2{pk2(ra.x, ra.y), pk2(ra.z, ra.w)};
            __syncthreads();
        }
    }

    // fold mask into gate, pack bf16, zero acc
    u32 gateb[2][6][2];
    #pragma unroll
    for (int mt = 0; mt < 2; ++mt) {
        int rb = mg * 32 + mt * 16 + q * 4;
        float m0 = __shfl(mv, rb + 0, 64);
        float m1 = __shfl(mv, rb + 1, 64);
        float m2 = __shfl(mv, rb + 2, 64);
        float m3 = __shfl(mv, rb + 3, 64);
        #pragma unroll
        for (int nt = 0; nt < 6; ++nt) {
            gateb[mt][nt][0] = pk2(acc[mt][nt][0] * m0, acc[mt][nt][1] * m1);
            gateb[mt][nt][1] = pk2(acc[mt][nt][2] * m2, acc[mt][nt][3] * m3);
            acc[mt][nt] = ZERO;
        }
    }

    // -------- Phase 2: s_proj = s @ Ws (kd=384, NK=12) --------
    {
        const int kd = C_;
        const float* ap = s_ij + (rowbase + arow) * kd + aseg * 4;
        const u16* wb = Wts + (cb + ln) * kd + q * 8;

        ra = *reinterpret_cast<const float4*>(ap);
        ap += 32;
        *reinterpret_cast<uint2*>(&ldsA[0][la_w]) = uint2{pk2(ra.x, ra.y), pk2(ra.z, ra.w)};
        __syncthreads();

        #pragma unroll 1
        for (int c = 0; c < 12; ++c) {
            if (c + 1 < 12) { ra = *reinterpret_cast<const float4*>(ap); ap += 32; }
            const u16* lA = ldsA[c & 1];
            bf16x8 a0 = *reinterpret_cast<const bf16x8*>(&lA[(mg * 32 + ln) * PAD + q * 8]);
            bf16x8 a1 = *reinterpret_cast<const bf16x8*>(&lA[(mg * 32 + 16 + ln) * PAD + q * 8]);
            bf16x8 b[6];
            #pragma unroll
            for (int nt = 0; nt < 6; ++nt)
                b[nt] = *reinterpret_cast<const bf16x8*>(wb + nt * 16 * kd);
            wb += 32;
            #pragma unroll
            for (int nt = 0; nt < 6; ++nt) {
                acc[0][nt] = __builtin_amdgcn_mfma_f32_16x16x32_bf16(a0, b[nt], acc[0][nt], 0, 0, 0);
                acc[1][nt] = __builtin_amdgcn_mfma_f32_16x16x32_bf16(a1, b[nt], acc[1][nt], 0, 0, 0);
            }
            if (c + 1 < 12)
                *reinterpret_cast<uint2*>(&ldsA[(c + 1) & 1][la_w]) =
                    uint2{pk2(ra.x, ra.y), pk2(ra.z, ra.w)};
            __syncthreads();
        }
    }

    // -------- Epilogue: msg + neighbor reduction --------
    // acc row = mg*32 + mt*16 + q*4 + r ; col = cb + nt*16 + ln
    #pragma unroll
    for (int nt = 0; nt < 6; ++nt) {
        int col = cb + nt * 16 + ln;
        float si = s_i[(long)(site0 + mg) * C_ + col];
        float p = 0.f;
        #pragma unroll
        for (int mt = 0; mt < 2; ++mt) {
            #pragma unroll
            for (int r = 0; r < 4; ++r) {
                float g = bfbits2f((u16)(gateb[mt][nt][r >> 1] >> ((r & 1) * 16)));
                p += (acc[mt][nt][r] - si) * g;
            }
        }
        p += __shfl_xor(p, 16, 64);
        p += __shfl_xor(p, 32, 64);
        if (q == 0) lds_snew[mg * C_ + col] = p;
    }
    __syncthreads();

    // -------- LayerNorm: wave 0 -> site0, wave 1 -> site1 --------
    if (wave < SPB) {
        const int site = wave;
        float v[6];
        float sum = 0.f, sumsq = 0.f;
        #pragma unroll
        for (int i = 0; i < 6; ++i) {
            v[i] = lds_snew[site * C_ + lane + i * 64];
            sum += v[i];
            sumsq += v[i] * v[i];
        }
        #pragma unroll
        for (int off = 32; off >= 1; off >>= 1) {
            sum += __shfl_xor(sum, off, 64);
            sumsq += __shfl_xor(sumsq, off, 64);
        }
        float mu = sum * (1.f / C_);
        float var = sumsq * (1.f / C_) - mu * mu;
        float rs = rsqrtf(var + EPSV);
        #pragma unroll
        for (int i = 0; i < 6; ++i) {
            int col = lane + i * 64;
            out[(long)(site0 + site) * C_ + col] = (v[i] - mu) * rs * gamma[col] + beta[col];
        }
    }
}

extern "C" void kernel_launch(void* const* d_in, const int* in_sizes, int n_in,
                              void* d_out, int out_size, void* d_ws, size_t ws_size,
                              hipStream_t stream) {
    (void)in_sizes; (void)n_in; (void)out_size; (void)ws_size;
    const float* s_i   = (const float*)d_in[0];
    const float* s_ij  = (const float*)d_in[1];
    const float* m_ij  = (const float*)d_in[2];
    const float* z_ij  = (const float*)d_in[3];
    const float* W_s   = (const float*)d_in[4];
    const float* W_z   = (const float*)d_in[5];
    const float* gamma = (const float*)d_in[6];
    const float* beta  = (const float*)d_in[7];
    float* out = (float*)d_out;

    u16* wts = (u16*)d_ws;             // 384*384 bf16
    u16* wtz = wts + C_ * C_;          // 384*128 bf16

    int prep_elems = C_ * C_ + C_ * CZ_;
    prep_weights<<<(prep_elems + 255) / 256, 256, 0, stream>>>(W_s, W_z, wts, wtz);
    fused_msg_kernel<<<NSITES / SPB, THREADS, 0, stream>>>(s_i, s_ij, m_ij, z_ij, wts, wtz,
                                                           gamma, beta, out);
}